// Round 6
// baseline (146.161 us; speedup 1.0000x reference)
//
#include <hip/hip_runtime.h>

// ElectronGNN on MI355X (gfx950).  Inputs float32, output float32.
// Round 14: phase-fission round — restructure per-wave stream at fixed occupancy.
//   r8/r9/r13 all ~70-78us regardless of barrier count => latency-bound at
//   2 waves/SIMD (grid-capped: 512 blocks x 4 waves on 1024 SIMDs; bigger
//   blocks spill, r10-r12).  Fix the per-wave schedule instead:
//   [z-block] zpass(0)->zst1, zpass(1)->zst2 back-to-back (VALU-heavy, 16
//   independent MFMA chains, all LDS reads pipelined), then
//   [gemm-block] gemm0,gemm1,zn,gemm2,gemm3 contiguous (load/MFMA-heavy,
//   B-frags direct from L2-resident wsegs, loads prefetch under MFMAs).
//   Supporting: weS/weA pre-packed to LDS h2 pairs at init (zpass wp: 64
//   global scalar -> 32 ds_read_b32); aS/aA reg-cache dropped, A-frags
//   recomputed from LDS positions (r12-proven) — frees ~64 VGPRs for
//   prefetch depth; (256,2) => 256-VGPR cap, no spill risk.
//   512 blocks x 256 threads, 1 batch/block, 4 barriers total.
//   LDS 65,792 B: xb + zst1 + zst2 + positions + packed weS/weA.
// d_ws: 491,520 B (r7-proven size, unchanged).

typedef unsigned short u16;
typedef unsigned int u32;
typedef __attribute__((ext_vector_type(8))) short short8;
typedef __attribute__((ext_vector_type(4))) float f32x4;
typedef __attribute__((ext_vector_type(4))) u32 u32x4;
typedef _Float16 h2 __attribute__((ext_vector_type(2)));

__device__ __forceinline__ u16 f2h(float f){ return __builtin_bit_cast(u16, (_Float16)f); }
__device__ __forceinline__ float h2f(u16 a){ return (float)__builtin_bit_cast(_Float16, a); }

__device__ __forceinline__ short8 rbf8(float dd){
  short8 a;
#pragma unroll
  for (int f = 0; f < 8; f++){
    float u = dd - (4.0f/7.0f)*(float)f;
    a[f] = (short)f2h(__expf(-u*u));
  }
  return a;
}

// ---------------- prep: frag-linear weight slabs (r7-proven, unchanged) ----------------
__global__ __launch_bounds__(256) void gnn_prep(
    const float* __restrict__ w_up, const float* __restrict__ we_ne,
    const float* __restrict__ embed, const int* __restrict__ atypes,
    u16* __restrict__ wsegs){
  __shared__ u16 lw[16384];
  const int blk = blockIdx.x;          // l*5 + seg
  const int l = blk / 5, seg = blk % 5;
  const int tid = threadIdx.x;
  if (seg < 4){
    const float* src = w_up + (l*512 + seg*128)*128;
#pragma unroll
    for (int mm = 0; mm < 16; mm++){
      int idx = mm*1024 + tid*4;
      float4 v = *(const float4*)(src + idx);
      lw[idx+0] = f2h(v.x); lw[idx+1] = f2h(v.y);
      lw[idx+2] = f2h(v.z); lw[idx+3] = f2h(v.w);
    }
  } else {
#pragma unroll
    for (int mm = 0; mm < 16; mm++){
      int idx = mm*1024 + tid*4;
      int k = idx >> 7, dout = idx & 127;
      int n = k >> 3, f = k & 7;
      float4 ye = *(const float4*)(embed + atypes[n]*128 + dout);
      float4 wn = *(const float4*)(we_ne + (l*8 + f)*128 + dout);
      lw[idx+0] = f2h(ye.x*wn.x); lw[idx+1] = f2h(ye.y*wn.y);
      lw[idx+2] = f2h(ye.z*wn.z); lw[idx+3] = f2h(ye.w*wn.w);
    }
  }
  __syncthreads();
  u16* dst = wsegs + blk*16384;
  const int col = tid & 15, q = (tid >> 4) & 3;
#pragma unroll
  for (int m = 0; m < 8; m++){
    int slot = m*4 + (tid >> 6);
    int c = slot >> 3, nt = slot & 7;
    int kbase = c*32 + q*8;
    int dout = nt*16 + col;
    short8 vv;
#pragma unroll
    for (int jj = 0; jj < 8; jj++) vv[jj] = (short)lw[(kbase+jj)*128 + dout];
    *(short8*)(dst + m*2048 + tid*8) = vv;
  }
}

// ---------------- main ----------------
__global__ __launch_bounds__(256, 2) void gnn_main(
    const float* __restrict__ r_g, const float* __restrict__ R_g,
    const float* __restrict__ weS_g, const float* __restrict__ weA_g,
    const float* __restrict__ bup_g,
    const u16* __restrict__ wsegs,
    float* __restrict__ out)
{
  extern __shared__ __attribute__((aligned(16))) u16 lds[];
  u16* const xb   = lds;                    // [64][136]
  u16* const zst1 = lds + 8704;             // [64][136] wave-private rows
  u16* const zst2 = lds + 17408;            // [64][136] wave-private rows
  float* const rs = (float*)(lds + 26112);  // [64][4] electron positions
  float* const Rs = rs + 256;               // [16][4] nuclei positions
  u32* const weP  = (u32*)(lds + 26752);    // [(l*2+pass)*4+p][128] h2-packed weS/weA

  const int tid  = threadIdx.x;
  const int lane = tid & 63;
  const int w    = tid >> 6;            // 0..3 (row-tile within batch)
  const int b    = blockIdx.x;          // one batch per block
  const int col  = lane & 15;
  const int q    = lane >> 4;
  const int i0   = w * 16;
  const int sp   = w >> 1;              // spin group of rows
  const int mrow = i0 + col;
  const int loff = (q*16 + col) * 8;

  // full-width GEMM: K=128 (4 chunks), N=128 (8 tiles).
  // A from row-major LDS; B direct from global wseg (L2-hot, coalesced dwordx4).
  auto gemm_seg = [&](const u16* wseg_g, const u16* arows, f32x4* acc){
#pragma unroll
    for (int c = 0; c < 4; c++){
      short8 a = *(const short8*)(arows + mrow*136 + c*32 + (q<<3));
#pragma unroll
      for (int nt = 0; nt < 8; nt++){
        short8 bf = *(const short8*)(wseg_g + c*4096 + nt*512 + loff);
        acc[nt] = __builtin_amdgcn_mfma_f32_16x16x32_f16(a, bf, acc[nt], 0, 0, 0);
      }
    }
  };

  // ---------------- init: positions, dN, weP pack, x init ----------------
  float px0, px1, px2;
  float dN[4];
  {
    if (tid < 64){
#pragma unroll
      for (int k = 0; k < 3; k++) rs[tid*4+k] = r_g[(b*64+tid)*3 + k];
    } else if (tid < 80){
      int n = tid - 64;
#pragma unroll
      for (int k = 0; k < 3; k++) Rs[n*4+k] = R_g[(b*16+n)*3 + k];
    }
    // pack weS/weA -> LDS as h2 pairs: weP[((l*2+pass)*4+p)*128 + d]
#pragma unroll
    for (int e0 = 0; e0 < 3072; e0 += 256){
      int e = e0 + tid;
      int d = e & 127, p = (e >> 7) & 3, ps = (e >> 9) & 1, ll = e >> 10;
      const float* src = ps ? weA_g : weS_g;
      h2 t;
      t[0] = (_Float16)src[(ll*8 + 2*p  )*128 + d];
      t[1] = (_Float16)src[(ll*8 + 2*p+1)*128 + d];
      weP[((ll*2+ps)*4 + p)*128 + d] = __builtin_bit_cast(u32, t);
    }
    __syncthreads();
    px0 = rs[mrow*4]; px1 = rs[mrow*4+1]; px2 = rs[mrow*4+2];
#pragma unroll
    for (int c = 0; c < 4; c++){
      int n = 4*c + q;
      float dx = px0-Rs[n*4], dy = px1-Rs[n*4+1], dz = px2-Rs[n*4+2];
      dN[c] = sqrtf(dx*dx + dy*dy + dz*dz + 1e-12f);
    }
    {
      int i = tid >> 2, nb = (tid & 3)*4;          // 256 threads: 4 cells each
      float y0 = rs[i*4], y1 = rs[i*4+1], y2 = rs[i*4+2];
#pragma unroll
      for (int nn = 0; nn < 4; nn++){
        int n = nb + nn;
        float dx = y0-Rs[n*4], dy = y1-Rs[n*4+1], dz = y2-Rs[n*4+2];
        float dd = sqrtf(dx*dx + dy*dy + dz*dz + 1e-12f);
        *(short8*)&xb[i*136 + n*8] = rbf8(dd);
      }
    }
    __syncthreads();       // xb + weP visible to all waves
  }

  f32x4 xr[8];
#pragma unroll
  for (int nt = 0; nt < 8; nt++)
#pragma unroll
    for (int rr = 0; rr < 4; rr++)
      xr[nt][rr] = h2f(xb[(i0 + q*4 + rr)*136 + nt*16 + col]);

  const f32x4 vzero = {0.f, 0.f, 0.f, 0.f};

#pragma unroll 1
  for (int l = 0; l < 3; l++){
    const u16* slab = wsegs + l*81920;

    f32x4 upd[8];
#pragma unroll
    for (int nt = 0; nt < 8; nt++) upd[nt] = vzero;

    // z-production: A-frags recomputed from LDS positions (r12-proven),
    // wp from LDS h2-packed weP (32 pipelined ds_read_b32, hoisted).
    auto zpass = [&](int pass, u16* zdst){
      const int jb0 = pass ? 32*(1-sp) : 32*sp;
      const u32* wbase = weP + ((l*2 + pass)*4)*128;
      h2 wpA[8][4];
#pragma unroll
      for (int nt = 0; nt < 8; nt++)
#pragma unroll
        for (int p = 0; p < 4; p++)
          wpA[nt][p] = __builtin_bit_cast(h2, wbase[p*128 + nt*16 + col]);
      f32x4 zacc[8];
#pragma unroll
      for (int nt = 0; nt < 8; nt++) zacc[nt] = vzero;
#pragma unroll
      for (int c = 0; c < 8; c++){
        int j = jb0 + 4*c + q;
        float dx = px0-rs[j*4], dy = px1-rs[j*4+1], dz = px2-rs[j*4+2];
        float dd = sqrtf(dx*dx + dy*dy + dz*dz + 1e-12f);
        short8 a = rbf8(dd);
        if (pass == 0 && j == mrow) a = (short8)0;   // no self-interaction
#pragma unroll
        for (int nt = 0; nt < 8; nt++){
          u16 xvv = xb[j*136 + nt*16 + col];
          _Float16 xh = __builtin_bit_cast(_Float16, xvv);
          h2 xd; xd[0] = xh; xd[1] = xh;
          u32x4 bu;
#pragma unroll
          for (int p = 0; p < 4; p++)
            bu[p] = __builtin_bit_cast(u32, (h2)(xd * wpA[nt][p]));
          short8 bf = __builtin_bit_cast(short8, bu);
          zacc[nt] = __builtin_amdgcn_mfma_f32_16x16x32_f16(a, bf, zacc[nt], 0, 0, 0);
        }
      }
      // zdst rows wave-private: same-wave ds_write->ds_read is lgkm-ordered.
#pragma unroll
      for (int nt = 0; nt < 8; nt++)
#pragma unroll
        for (int rr = 0; rr < 4; rr++)
          zdst[(i0 + q*4 + rr)*136 + nt*16 + col] = f2h(zacc[nt][rr]);
    };

    // ---- z-block: both zpasses back-to-back (VALU-heavy, max ILP) ----
    zpass(0, zst1);
    zpass(1, zst2);

    // ---- gemm-block: contiguous load/MFMA stream ----
    gemm_seg(slab + 0*16384, xb,   upd);   // x  @ W0
    gemm_seg(slab + 1*16384, zst1, upd);   // zs @ W1
    {                                      // zn from Y seg -> zst1 (reuse)
      const u16* yseg = slab + 4*16384;
      f32x4 zn[8];
#pragma unroll
      for (int nt = 0; nt < 8; nt++) zn[nt] = vzero;
#pragma unroll
      for (int c = 0; c < 4; c++){
        short8 a = rbf8(dN[c]);
#pragma unroll
        for (int nt = 0; nt < 8; nt++){
          short8 bf = *(const short8*)(yseg + c*4096 + nt*512 + loff);
          zn[nt] = __builtin_amdgcn_mfma_f32_16x16x32_f16(a, bf, zn[nt], 0, 0, 0);
        }
      }
#pragma unroll
      for (int nt = 0; nt < 8; nt++)
#pragma unroll
        for (int rr = 0; rr < 4; rr++)
          zst1[(i0 + q*4 + rr)*136 + nt*16 + col] = f2h(zn[nt][rr]);
    }
    gemm_seg(slab + 2*16384, zst2, upd);   // za @ W2
    gemm_seg(slab + 3*16384, zst1, upd);   // zn @ W3

    // ---- epilogue ----
    {
      float bupr[8];
#pragma unroll
      for (int nt = 0; nt < 8; nt++) bupr[nt] = bup_g[l*128 + nt*16 + col];
#pragma unroll
      for (int nt = 0; nt < 8; nt++){
#pragma unroll
        for (int rr = 0; rr < 4; rr++){
          float v = upd[nt][rr] + bupr[nt];
          float e = __expf(2.0f * v);
          float th = 1.0f - 2.0f * __builtin_amdgcn_rcpf(e + 1.0f);
          xr[nt][rr] += th;
        }
      }
    }
    if (l < 2){
#pragma unroll
      for (int nt = 0; nt < 8; nt++)
#pragma unroll
        for (int rr = 0; rr < 4; rr++)
          xb[(i0 + q*4 + rr)*136 + nt*16 + col] = f2h(xr[nt][rr]);
      __syncthreads();     // xb cross-wave: next layer's zpass reads all rows
    } else {
#pragma unroll
      for (int nt = 0; nt < 8; nt++)
#pragma unroll
        for (int rr = 0; rr < 4; rr++)
          out[(b*64 + i0 + q*4 + rr)*128 + nt*16 + col] = xr[nt][rr];
    }
  }
}

extern "C" void kernel_launch(void* const* d_in, const int* in_sizes, int n_in,
                              void* d_out, int out_size, void* d_ws, size_t ws_size,
                              hipStream_t stream){
  const float* r     = (const float*)d_in[0];
  const float* R     = (const float*)d_in[1];
  const float* embed = (const float*)d_in[2];
  const float* weS   = (const float*)d_in[3];
  const float* weA   = (const float*)d_in[4];
  const float* weN   = (const float*)d_in[5];
  const float* wup   = (const float*)d_in[6];
  const float* bup   = (const float*)d_in[7];
  const int* atyp    = (const int*)d_in[8];

  u16* wsegs = (u16*)d_ws;                // 3*5*16384 fp16 = 491,520 B (proven size)

  (void)hipFuncSetAttribute((const void*)gnn_main,
                            hipFuncAttributeMaxDynamicSharedMemorySize, 65792);
  gnn_prep<<<15, 256, 0, stream>>>(wup, weN, embed, atyp, wsegs);
  gnn_main<<<512, 256, 65792, stream>>>(r, R, weS, weA, bup, wsegs, (float*)d_out);
}